// Round 1
// baseline (2396.955 us; speedup 1.0000x reference)
//
#include <hip/hip_runtime.h>
#include <hip/hip_bf16.h>

typedef unsigned short u16;
typedef short bf16x8 __attribute__((ext_vector_type(8)));
typedef float f32x4 __attribute__((ext_vector_type(4)));

// ---------- helpers ----------
__device__ __forceinline__ unsigned pk2(float lo, float hi) {
    unsigned a = (unsigned)__builtin_bit_cast(u16, __float2bfloat16(lo));
    unsigned b = (unsigned)__builtin_bit_cast(u16, __float2bfloat16(hi));
    return a | (b << 16);
}
__device__ __forceinline__ u16 f2bf(float v) {
    return __builtin_bit_cast(u16, __float2bfloat16(v));
}

// ---------- f32 -> bf16 weight convert ----------
__global__ void cvtbf(const float4* __restrict__ s, uint2* __restrict__ d, int n4) {
    int i = blockIdx.x * blockDim.x + threadIdx.x;
    int stride = gridDim.x * blockDim.x;
    for (; i < n4; i += stride) {
        float4 f = s[i];
        uint2 o;
        o.x = pk2(f.x, f.y);
        o.y = pk2(f.z, f.w);
        d[i] = o;
    }
}

// ---------- GEMM1: h = GELU(x @ W1^T + b1), x = [u_t | emb[s_i]] ----------
// M=65536, N=2048, K=1536.  A built on the fly (f32->bf16), B = w1b bf16 [2048][1536].
__global__ __launch_bounds__(256, 2) void gemm1_gelu(
    const float* __restrict__ u_t, const float* __restrict__ emb,
    const int* __restrict__ s_i, const u16* __restrict__ w1b,
    const float* __restrict__ b1, u16* __restrict__ hbuf) {
    __shared__ __align__(16) u16 As[2][128 * 64];
    __shared__ __align__(16) u16 Bs[2][128 * 64];
    __shared__ int sRow[128];

    const int tid = threadIdx.x;
    const int cpx = gridDim.x >> 3;  // XCD swizzle (8192 % 8 == 0)
    const int tile = ((int)blockIdx.x & 7) * cpx + ((int)blockIdx.x >> 3);
    const int tm = tile >> 4;
    const int tn = tile & 15;
    const long rowBase = (long)tm * 128;
    const long colBase = (long)tn * 128;

    if (tid < 128) sRow[tid] = s_i[rowBase + tid];

    // staging map: 16B LDS chunk cc (8 bf16), rows r0+32i
    const int cc = tid & 7;
    const int r0 = tid >> 3;
    int wofs[4];
#pragma unroll
    for (int i = 0; i < 4; ++i) {
        int r = r0 + 32 * i;
        wofs[i] = r * 64 + ((cc ^ (r & 7)) << 3);
    }

    // compute map
    const int lane = tid & 63;
    const int wv = tid >> 6;
    const int wr = wv >> 1, wc = wv & 1;
    int offA[2][4], offB[2][4];
#pragma unroll
    for (int kk2 = 0; kk2 < 2; ++kk2) {
#pragma unroll
        for (int m = 0; m < 4; ++m) {
            int r = wr * 64 + m * 16 + (lane & 15);
            int ch = (kk2 * 4 + (lane >> 4)) ^ (r & 7);
            offA[kk2][m] = r * 64 + (ch << 3);
            int c = wc * 64 + m * 16 + (lane & 15);
            int chb = (kk2 * 4 + (lane >> 4)) ^ (c & 7);
            offB[kk2][m] = c * 64 + (chb << 3);
        }
    }

    f32x4 acc[4][4];
    const f32x4 zero = {0.f, 0.f, 0.f, 0.f};
#pragma unroll
    for (int m = 0; m < 4; ++m)
#pragma unroll
        for (int n = 0; n < 4; ++n) acc[m][n] = zero;

    float4 la0[4], la1[4];
    uint4 lb[4];

    auto loadA = [&](int kt) {
        if (kt < 12) {
            const float* p0 = u_t + rowBase * 768 + kt * 64 + cc * 8;
#pragma unroll
            for (int i = 0; i < 4; ++i) {
                const float* p = p0 + (long)(r0 + 32 * i) * 768;
                la0[i] = *(const float4*)p;
                la1[i] = *(const float4*)(p + 4);
            }
        } else {
            const int koff = kt * 64 - 768 + cc * 8;
#pragma unroll
            for (int i = 0; i < 4; ++i) {
                const float* p = emb + (long)sRow[r0 + 32 * i] * 768 + koff;
                la0[i] = *(const float4*)p;
                la1[i] = *(const float4*)(p + 4);
            }
        }
    };
    auto loadB = [&](int kt) {
        const u16* p0 = w1b + colBase * 1536 + kt * 64 + cc * 8;
#pragma unroll
        for (int i = 0; i < 4; ++i)
            lb[i] = *(const uint4*)(p0 + (long)(r0 + 32 * i) * 1536);
    };
    auto storeLDS = [&](int buf) {
#pragma unroll
        for (int i = 0; i < 4; ++i) {
            uint4 ua;
            ua.x = pk2(la0[i].x, la0[i].y);
            ua.y = pk2(la0[i].z, la0[i].w);
            ua.z = pk2(la1[i].x, la1[i].y);
            ua.w = pk2(la1[i].z, la1[i].w);
            *(uint4*)&As[buf][wofs[i]] = ua;
            *(uint4*)&Bs[buf][wofs[i]] = lb[i];
        }
    };
    auto compute = [&](int buf) {
#pragma unroll
        for (int kk2 = 0; kk2 < 2; ++kk2) {
            bf16x8 af[4], bfr[4];
#pragma unroll
            for (int m = 0; m < 4; ++m) af[m] = *(const bf16x8*)&As[buf][offA[kk2][m]];
#pragma unroll
            for (int n = 0; n < 4; ++n) bfr[n] = *(const bf16x8*)&Bs[buf][offB[kk2][n]];
#pragma unroll
            for (int m = 0; m < 4; ++m)
#pragma unroll
                for (int n = 0; n < 4; ++n)
                    acc[m][n] = __builtin_amdgcn_mfma_f32_16x16x32_bf16(af[m], bfr[n], acc[m][n], 0, 0, 0);
        }
    };

    loadA(0);
    loadB(0);
    storeLDS(0);
    int cur = 0;
    for (int kt = 0; kt < 24; ++kt) {
        if (kt + 1 < 24) { loadA(kt + 1); loadB(kt + 1); }
        __syncthreads();
        compute(cur);
        if (kt + 1 < 24) { storeLDS(cur ^ 1); cur ^= 1; }
    }

    const float* b1p = b1 + colBase;
#pragma unroll
    for (int n = 0; n < 4; ++n) {
        int gcl = wc * 64 + n * 16 + (lane & 15);
        float bias = b1p[gcl];
        long gc = colBase + gcl;
#pragma unroll
        for (int m = 0; m < 4; ++m) {
            long gr = rowBase + wr * 64 + m * 16 + ((lane >> 4) << 2);
            u16* dst = hbuf + gr * 2048 + gc;
#pragma unroll
            for (int j = 0; j < 4; ++j) {
                float v = acc[m][n][j] + bias;
                v = 0.5f * v * (1.0f + erff(v * 0.70710678118f));
                dst[(long)j * 2048] = f2bf(v);
            }
        }
    }
}

// ---------- GEMM2: y = h @ W2^T + b2 ----------
// M=65536, N=768, K=2048. A = hbuf bf16 [B][2048], B = w2b bf16 [768][2048].
__global__ __launch_bounds__(256, 2) void gemm2_bias(
    const u16* __restrict__ hbuf, const u16* __restrict__ w2b,
    const float* __restrict__ b2, float* __restrict__ yout) {
    __shared__ __align__(16) u16 As[2][128 * 64];
    __shared__ __align__(16) u16 Bs[2][128 * 64];

    const int tid = threadIdx.x;
    const int cpx = gridDim.x >> 3;  // 3072 % 8 == 0
    const int tile = ((int)blockIdx.x & 7) * cpx + ((int)blockIdx.x >> 3);
    const int tm = tile / 6;
    const int tn = tile % 6;
    const long rowBase = (long)tm * 128;
    const long colBase = (long)tn * 128;

    const int cc = tid & 7;
    const int r0 = tid >> 3;
    int wofs[4];
#pragma unroll
    for (int i = 0; i < 4; ++i) {
        int r = r0 + 32 * i;
        wofs[i] = r * 64 + ((cc ^ (r & 7)) << 3);
    }

    const int lane = tid & 63;
    const int wv = tid >> 6;
    const int wr = wv >> 1, wc = wv & 1;
    int offA[2][4], offB[2][4];
#pragma unroll
    for (int kk2 = 0; kk2 < 2; ++kk2) {
#pragma unroll
        for (int m = 0; m < 4; ++m) {
            int r = wr * 64 + m * 16 + (lane & 15);
            int ch = (kk2 * 4 + (lane >> 4)) ^ (r & 7);
            offA[kk2][m] = r * 64 + (ch << 3);
            int c = wc * 64 + m * 16 + (lane & 15);
            int chb = (kk2 * 4 + (lane >> 4)) ^ (c & 7);
            offB[kk2][m] = c * 64 + (chb << 3);
        }
    }

    f32x4 acc[4][4];
    const f32x4 zero = {0.f, 0.f, 0.f, 0.f};
#pragma unroll
    for (int m = 0; m < 4; ++m)
#pragma unroll
        for (int n = 0; n < 4; ++n) acc[m][n] = zero;

    uint4 la[4], lb[4];
    auto loadAB = [&](int kt) {
        const u16* pa = hbuf + rowBase * 2048 + kt * 64 + cc * 8;
        const u16* pb = w2b + colBase * 2048 + kt * 64 + cc * 8;
#pragma unroll
        for (int i = 0; i < 4; ++i) {
            la[i] = *(const uint4*)(pa + (long)(r0 + 32 * i) * 2048);
            lb[i] = *(const uint4*)(pb + (long)(r0 + 32 * i) * 2048);
        }
    };
    auto storeLDS = [&](int buf) {
#pragma unroll
        for (int i = 0; i < 4; ++i) {
            *(uint4*)&As[buf][wofs[i]] = la[i];
            *(uint4*)&Bs[buf][wofs[i]] = lb[i];
        }
    };
    auto compute = [&](int buf) {
#pragma unroll
        for (int kk2 = 0; kk2 < 2; ++kk2) {
            bf16x8 af[4], bfr[4];
#pragma unroll
            for (int m = 0; m < 4; ++m) af[m] = *(const bf16x8*)&As[buf][offA[kk2][m]];
#pragma unroll
            for (int n = 0; n < 4; ++n) bfr[n] = *(const bf16x8*)&Bs[buf][offB[kk2][n]];
#pragma unroll
            for (int m = 0; m < 4; ++m)
#pragma unroll
                for (int n = 0; n < 4; ++n)
                    acc[m][n] = __builtin_amdgcn_mfma_f32_16x16x32_bf16(af[m], bfr[n], acc[m][n], 0, 0, 0);
        }
    };

    loadAB(0);
    storeLDS(0);
    int cur = 0;
    for (int kt = 0; kt < 32; ++kt) {
        if (kt + 1 < 32) loadAB(kt + 1);
        __syncthreads();
        compute(cur);
        if (kt + 1 < 32) { storeLDS(cur ^ 1); cur ^= 1; }
    }

    const float* b2p = b2 + colBase;
#pragma unroll
    for (int n = 0; n < 4; ++n) {
        int gcl = wc * 64 + n * 16 + (lane & 15);
        float bias = b2p[gcl];
        long gc = colBase + gcl;
#pragma unroll
        for (int m = 0; m < 4; ++m) {
            long gr = rowBase + wr * 64 + m * 16 + ((lane >> 4) << 2);
            float* dst = yout + gr * 768 + gc;
#pragma unroll
            for (int j = 0; j < 4; ++j) dst[(long)j * 768] = acc[m][n][j] + bias;
        }
    }
}

// ---------- LayerNorm in place on y [B,768] ----------
__global__ __launch_bounds__(256) void ln_kernel(float* __restrict__ y,
                                                 const float* __restrict__ gamma,
                                                 const float* __restrict__ beta) {
    const int lane = threadIdx.x & 63;
    const long row = (long)blockIdx.x * 4 + (threadIdx.x >> 6);
    const long base = row * 768;
    float v[12];
#pragma unroll
    for (int i = 0; i < 12; ++i) v[i] = y[base + i * 64 + lane];
    float s = 0.f, q = 0.f;
#pragma unroll
    for (int i = 0; i < 12; ++i) { s += v[i]; q += v[i] * v[i]; }
#pragma unroll
    for (int off = 32; off > 0; off >>= 1) {
        s += __shfl_xor(s, off, 64);
        q += __shfl_xor(q, off, 64);
    }
    const float mu = s * (1.f / 768.f);
    const float var = q * (1.f / 768.f) - mu * mu;
    const float inv = rsqrtf(var + 1e-5f);
#pragma unroll
    for (int i = 0; i < 12; ++i) {
        int c = i * 64 + lane;
        y[base + c] = (v[i] - mu) * inv * gamma[c] + beta[c];
    }
}

// ---------- copy speaker_embeddings -> updated ----------
__global__ void copy4(const float4* __restrict__ s, float4* __restrict__ d, long n) {
    long i = (long)blockIdx.x * blockDim.x + threadIdx.x;
    long stride = (long)gridDim.x * blockDim.x;
    for (; i < n; i += stride) d[i] = s[i];
}

// ---------- scatter-add new_h_t into updated ----------
__global__ __launch_bounds__(256) void scatter_add(const float* __restrict__ newh,
                                                   const int* __restrict__ s_i,
                                                   float* __restrict__ upd) {
    const int lane = threadIdx.x & 63;
    const long b = (long)blockIdx.x * 4 + (threadIdx.x >> 6);
    const long s = s_i[b];
#pragma unroll
    for (int i = 0; i < 12; ++i) {
        int c = i * 64 + lane;
        atomicAdd(&upd[s * 768 + c], newh[b * 768 + c]);
    }
}

extern "C" void kernel_launch(void* const* d_in, const int* in_sizes, int n_in,
                              void* d_out, int out_size, void* d_ws, size_t ws_size,
                              hipStream_t stream) {
    const float* u_t = (const float*)d_in[0];
    const int* s_i = (const int*)d_in[1];
    const float* emb = (const float*)d_in[2];
    const float* W1 = (const float*)d_in[3];
    const float* b1 = (const float*)d_in[4];
    const float* W2 = (const float*)d_in[5];
    const float* b2 = (const float*)d_in[6];
    const float* gamma = (const float*)d_in[7];
    const float* beta = (const float*)d_in[8];

    float* out = (float*)d_out;
    float* newh = out;                    // [65536,768] f32 (y then LN in place)
    float* upd = out + 50331648L;         // [262144,768] f32 (scratch first, then final)
    u16* hbuf = (u16*)upd;                // [65536,2048] bf16 scratch (268 MB)
    u16* w1b = (u16*)(upd + 67108864L);   // [2048,1536] bf16
    u16* w2b = w1b + 3145728L;            // [768,2048] bf16

    cvtbf<<<1024, 256, 0, stream>>>((const float4*)W1, (uint2*)w1b, 786432);
    cvtbf<<<1024, 256, 0, stream>>>((const float4*)W2, (uint2*)w2b, 393216);
    gemm1_gelu<<<8192, 256, 0, stream>>>(u_t, emb, s_i, w1b, b1, hbuf);
    gemm2_bias<<<3072, 256, 0, stream>>>(hbuf, w2b, b2, newh);
    ln_kernel<<<16384, 256, 0, stream>>>(newh, gamma, beta);
    copy4<<<2048, 256, 0, stream>>>((const float4*)emb, (float4*)upd, 50331648L);
    scatter_add<<<16384, 256, 0, stream>>>(newh, s_i, upd);
}

// Round 2
// 1544.225 us; speedup vs baseline: 1.5522x; 1.5522x over previous
//
#include <hip/hip_runtime.h>
#include <hip/hip_bf16.h>

typedef unsigned short u16;
typedef unsigned int u32;
typedef short bf16x8 __attribute__((ext_vector_type(8)));
typedef float f32x4 __attribute__((ext_vector_type(4)));

// ---------- helpers ----------
__device__ __forceinline__ unsigned pk2(float lo, float hi) {
    unsigned a = (unsigned)__builtin_bit_cast(u16, __float2bfloat16(lo));
    unsigned b = (unsigned)__builtin_bit_cast(u16, __float2bfloat16(hi));
    return a | (b << 16);
}
__device__ __forceinline__ u16 f2bf(float v) {
    return __builtin_bit_cast(u16, __float2bfloat16(v));
}
// async global->LDS, 16B per lane; lds dst = wave-uniform base + lane*16
__device__ __forceinline__ void gl_lds16(const u16* g, u16* l) {
    __builtin_amdgcn_global_load_lds(
        (const __attribute__((address_space(1))) u32*)g,
        (__attribute__((address_space(3))) u32*)l, 16, 0, 0);
}

// ---------- f32 -> bf16 weight convert ----------
__global__ void cvtbf(const float4* __restrict__ s, uint2* __restrict__ d, int n4) {
    int i = blockIdx.x * blockDim.x + threadIdx.x;
    int stride = gridDim.x * blockDim.x;
    for (; i < n4; i += stride) {
        float4 f = s[i];
        uint2 o;
        o.x = pk2(f.x, f.y);
        o.y = pk2(f.z, f.w);
        d[i] = o;
    }
}

// ---------- build x = [u_t | emb[s_i]] as bf16 [65536][1536] ----------
__global__ __launch_bounds__(256) void xbuild(const float* __restrict__ u_t,
                                              const float* __restrict__ emb,
                                              const int* __restrict__ s_i,
                                              u16* __restrict__ xb) {
    const long u = (long)blockIdx.x * blockDim.x + threadIdx.x;  // 12,582,912 units of 8
    const int row = (int)(u / 192);
    const int c8 = (int)(u % 192);
    const float* src = (c8 < 96) ? (u_t + (long)row * 768 + c8 * 8)
                                 : (emb + (long)s_i[row] * 768 + (c8 - 96) * 8);
    float4 f0 = ((const float4*)src)[0];
    float4 f1 = ((const float4*)src)[1];
    uint4 o;
    o.x = pk2(f0.x, f0.y);
    o.y = pk2(f0.z, f0.w);
    o.z = pk2(f1.x, f1.y);
    o.w = pk2(f1.z, f1.w);
    *(uint4*)(xb + u * 8) = o;
}

// ---------- GEMM1: h = GELU(xb @ w1b^T + b1) ----------
// M=65536, N=2048, K=1536 (LDK=1536, NT=24). m97 structure.
__global__ __launch_bounds__(256, 3) void gemm1_gelu(
    const u16* __restrict__ xb, const u16* __restrict__ w1b,
    const float* __restrict__ b1, u16* __restrict__ hbuf) {
    __shared__ __align__(16) u16 As[128 * 64];
    __shared__ __align__(16) u16 Bs[128 * 64];

    const int tid = threadIdx.x;
    const int lane = tid & 63;
    const int wv = tid >> 6;
    const int cpx = gridDim.x >> 3;  // 8192 % 8 == 0
    const int tile = ((int)blockIdx.x & 7) * cpx + ((int)blockIdx.x >> 3);
    const int tm = tile >> 4;
    const int tn = tile & 15;
    const long rowBase = (long)tm * 128;
    const long colBase = (long)tn * 128;

    // staging: per pass i, rows 32*i + 8*wv + (lane>>3), col chunk (lane&7)*8
    const u16* gA0 = xb + (rowBase + 8 * wv + (lane >> 3)) * 1536 + (lane & 7) * 8;
    const u16* gB0 = w1b + (colBase + 8 * wv + (lane >> 3)) * 1536 + (lane & 7) * 8;

    auto stage = [&](int kt) {
        const u16* ga = gA0 + kt * 64;
        const u16* gb = gB0 + kt * 64;
#pragma unroll
        for (int i = 0; i < 4; ++i) {
            gl_lds16(ga + (long)i * 32 * 1536, As + (32 * i + 8 * wv) * 64);
            gl_lds16(gb + (long)i * 32 * 1536, Bs + (32 * i + 8 * wv) * 64);
        }
    };

    const int wr = wv >> 1, wc = wv & 1;
    const u16* aBase = As + (wr * 64 + (lane & 15)) * 64 + (lane >> 4) * 8;
    const u16* bBase = Bs + (wc * 64 + (lane & 15)) * 64 + (lane >> 4) * 8;

    f32x4 acc[4][4];
    const f32x4 zero = {0.f, 0.f, 0.f, 0.f};
#pragma unroll
    for (int m = 0; m < 4; ++m)
#pragma unroll
        for (int n = 0; n < 4; ++n) acc[m][n] = zero;

    stage(0);
    for (int kt = 0; kt < 24; ++kt) {
        __syncthreads();  // drains vmcnt(0): staged data visible
#pragma unroll
        for (int kk = 0; kk < 2; ++kk) {
            bf16x8 a[4], b[4];
#pragma unroll
            for (int m = 0; m < 4; ++m) a[m] = *(const bf16x8*)(aBase + m * 16 * 64 + kk * 32);
#pragma unroll
            for (int n = 0; n < 4; ++n) b[n] = *(const bf16x8*)(bBase + n * 16 * 64 + kk * 32);
#pragma unroll
            for (int m = 0; m < 4; ++m)
#pragma unroll
                for (int n = 0; n < 4; ++n)
                    acc[m][n] = __builtin_amdgcn_mfma_f32_16x16x32_bf16(a[m], b[n], acc[m][n], 0, 0, 0);
        }
        if (kt + 1 < 24) {
            __syncthreads();  // all waves done reading LDS
            stage(kt + 1);
        }
    }

    const float* b1p = b1 + colBase;
#pragma unroll
    for (int n = 0; n < 4; ++n) {
        int gcl = wc * 64 + n * 16 + (lane & 15);
        float bias = b1p[gcl];
        long gc = colBase + gcl;
#pragma unroll
        for (int m = 0; m < 4; ++m) {
            long gr = rowBase + wr * 64 + m * 16 + ((lane >> 4) << 2);
            u16* dst = hbuf + gr * 2048 + gc;
#pragma unroll
            for (int j = 0; j < 4; ++j) {
                float v = acc[m][n][j] + bias;
                v = 0.5f * v * (1.0f + erff(v * 0.70710678118f));
                dst[(long)j * 2048] = f2bf(v);
            }
        }
    }
}

// ---------- GEMM2: y = hbuf @ w2b^T + b2 ----------
// M=65536, N=768, K=2048 (LDK=2048, NT=32). m97 structure.
__global__ __launch_bounds__(256, 3) void gemm2_bias(
    const u16* __restrict__ hbuf, const u16* __restrict__ w2b,
    const float* __restrict__ b2, float* __restrict__ yout) {
    __shared__ __align__(16) u16 As[128 * 64];
    __shared__ __align__(16) u16 Bs[128 * 64];

    const int tid = threadIdx.x;
    const int lane = tid & 63;
    const int wv = tid >> 6;
    const int cpx = gridDim.x >> 3;  // 3072 % 8 == 0
    const int tile = ((int)blockIdx.x & 7) * cpx + ((int)blockIdx.x >> 3);
    const int tm = tile / 6;
    const int tn = tile % 6;
    const long rowBase = (long)tm * 128;
    const long colBase = (long)tn * 128;

    const u16* gA0 = hbuf + (rowBase + 8 * wv + (lane >> 3)) * 2048 + (lane & 7) * 8;
    const u16* gB0 = w2b + (colBase + 8 * wv + (lane >> 3)) * 2048 + (lane & 7) * 8;

    auto stage = [&](int kt) {
        const u16* ga = gA0 + kt * 64;
        const u16* gb = gB0 + kt * 64;
#pragma unroll
        for (int i = 0; i < 4; ++i) {
            gl_lds16(ga + (long)i * 32 * 2048, As + (32 * i + 8 * wv) * 64);
            gl_lds16(gb + (long)i * 32 * 2048, Bs + (32 * i + 8 * wv) * 64);
        }
    };

    const int wr = wv >> 1, wc = wv & 1;
    const u16* aBase = As + (wr * 64 + (lane & 15)) * 64 + (lane >> 4) * 8;
    const u16* bBase = Bs + (wc * 64 + (lane & 15)) * 64 + (lane >> 4) * 8;

    f32x4 acc[4][4];
    const f32x4 zero = {0.f, 0.f, 0.f, 0.f};
#pragma unroll
    for (int m = 0; m < 4; ++m)
#pragma unroll
        for (int n = 0; n < 4; ++n) acc[m][n] = zero;

    stage(0);
    for (int kt = 0; kt < 32; ++kt) {
        __syncthreads();
#pragma unroll
        for (int kk = 0; kk < 2; ++kk) {
            bf16x8 a[4], b[4];
#pragma unroll
            for (int m = 0; m < 4; ++m) a[m] = *(const bf16x8*)(aBase + m * 16 * 64 + kk * 32);
#pragma unroll
            for (int n = 0; n < 4; ++n) b[n] = *(const bf16x8*)(bBase + n * 16 * 64 + kk * 32);
#pragma unroll
            for (int m = 0; m < 4; ++m)
#pragma unroll
                for (int n = 0; n < 4; ++n)
                    acc[m][n] = __builtin_amdgcn_mfma_f32_16x16x32_bf16(a[m], b[n], acc[m][n], 0, 0, 0);
        }
        if (kt + 1 < 32) {
            __syncthreads();
            stage(kt + 1);
        }
    }

    const float* b2p = b2 + colBase;
#pragma unroll
    for (int n = 0; n < 4; ++n) {
        int gcl = wc * 64 + n * 16 + (lane & 15);
        float bias = b2p[gcl];
        long gc = colBase + gcl;
#pragma unroll
        for (int m = 0; m < 4; ++m) {
            long gr = rowBase + wr * 64 + m * 16 + ((lane >> 4) << 2);
            float* dst = yout + gr * 768 + gc;
#pragma unroll
            for (int j = 0; j < 4; ++j) dst[(long)j * 768] = acc[m][n][j] + bias;
        }
    }
}

// ---------- LayerNorm (in place) + scatter-add into updated ----------
__global__ __launch_bounds__(256) void ln_scatter(float* __restrict__ y,
                                                  const float* __restrict__ gamma,
                                                  const float* __restrict__ beta,
                                                  const int* __restrict__ s_i,
                                                  float* __restrict__ upd) {
    const int lane = threadIdx.x & 63;
    const long row = (long)blockIdx.x * 4 + (threadIdx.x >> 6);
    const long base = row * 768;
    float v[12];
#pragma unroll
    for (int i = 0; i < 12; ++i) v[i] = y[base + i * 64 + lane];
    float s = 0.f, q = 0.f;
#pragma unroll
    for (int i = 0; i < 12; ++i) { s += v[i]; q += v[i] * v[i]; }
#pragma unroll
    for (int off = 32; off > 0; off >>= 1) {
        s += __shfl_xor(s, off, 64);
        q += __shfl_xor(q, off, 64);
    }
    const float mu = s * (1.f / 768.f);
    const float var = q * (1.f / 768.f) - mu * mu;
    const float inv = rsqrtf(var + 1e-5f);
    const long si = s_i[row];
#pragma unroll
    for (int i = 0; i < 12; ++i) {
        int c = i * 64 + lane;
        float r = (v[i] - mu) * inv * gamma[c] + beta[c];
        y[base + c] = r;
        atomicAdd(&upd[si * 768 + c], r);
    }
}

// ---------- copy speaker_embeddings -> updated ----------
__global__ void copy4(const float4* __restrict__ s, float4* __restrict__ d, long n) {
    long i = (long)blockIdx.x * blockDim.x + threadIdx.x;
    long stride = (long)gridDim.x * blockDim.x;
    for (; i < n; i += stride) d[i] = s[i];
}

extern "C" void kernel_launch(void* const* d_in, const int* in_sizes, int n_in,
                              void* d_out, int out_size, void* d_ws, size_t ws_size,
                              hipStream_t stream) {
    const float* u_t = (const float*)d_in[0];
    const int* s_i = (const int*)d_in[1];
    const float* emb = (const float*)d_in[2];
    const float* W1 = (const float*)d_in[3];
    const float* b1 = (const float*)d_in[4];
    const float* W2 = (const float*)d_in[5];
    const float* b2 = (const float*)d_in[6];
    const float* gamma = (const float*)d_in[7];
    const float* beta = (const float*)d_in[8];

    float* out = (float*)d_out;
    float* newh = out;             // [65536,768] f32 (y, then LN in place)
    float* upd = out + 50331648L;  // [262144,768] f32 (scratch first, final last)

    u16* base = (u16*)upd;
    u16* hbuf = base;                  // [65536,2048] bf16 (268 MB)
    u16* xb = base + 134217728L;       // [65536,1536] bf16 (201 MB)
    u16* w1b = base + 234881024L;      // [2048,1536] bf16
    u16* w2b = base + 238026752L;      // [768,2048] bf16

    cvtbf<<<1024, 256, 0, stream>>>((const float4*)W1, (uint2*)w1b, 786432);
    cvtbf<<<1024, 256, 0, stream>>>((const float4*)W2, (uint2*)w2b, 393216);
    xbuild<<<49152, 256, 0, stream>>>(u_t, emb, s_i, xb);
    gemm1_gelu<<<8192, 256, 0, stream>>>(xb, w1b, b1, hbuf);
    gemm2_bias<<<3072, 256, 0, stream>>>(hbuf, w2b, b2, newh);
    copy4<<<2048, 256, 0, stream>>>((const float4*)emb, (float4*)upd, 50331648L);
    ln_scatter<<<16384, 256, 0, stream>>>(newh, gamma, beta, s_i, upd);
}

// Round 4
// 1389.666 us; speedup vs baseline: 1.7248x; 1.1112x over previous
//
#include <hip/hip_runtime.h>
#include <hip/hip_bf16.h>

typedef unsigned short u16;
typedef unsigned int u32;
typedef short bf16x8 __attribute__((ext_vector_type(8)));
typedef float f32x4 __attribute__((ext_vector_type(4)));

#define BAR() asm volatile("s_barrier" ::: "memory")
#define WAITV4() asm volatile("s_waitcnt vmcnt(4)" ::: "memory")
#define WAITV0() asm volatile("s_waitcnt vmcnt(0)" ::: "memory")
#define WAITL() asm volatile("s_waitcnt lgkmcnt(0)" ::: "memory")

// ---------- helpers ----------
__device__ __forceinline__ unsigned pk2(float lo, float hi) {
    unsigned a = (unsigned)__builtin_bit_cast(u16, __float2bfloat16(lo));
    unsigned b = (unsigned)__builtin_bit_cast(u16, __float2bfloat16(hi));
    return a | (b << 16);
}
__device__ __forceinline__ u16 f2bf(float v) {
    return __builtin_bit_cast(u16, __float2bfloat16(v));
}
__device__ __forceinline__ void gl_lds16(const u16* g, u16* l) {
    __builtin_amdgcn_global_load_lds(
        (const __attribute__((address_space(1))) u32*)g,
        (__attribute__((address_space(3))) u32*)l, 16, 0, 0);
}

// ---------- f32 -> bf16 weight convert ----------
__global__ void cvtbf(const float4* __restrict__ s, uint2* __restrict__ d, int n4) {
    int i = blockIdx.x * blockDim.x + threadIdx.x;
    int stride = gridDim.x * blockDim.x;
    for (; i < n4; i += stride) {
        float4 f = s[i];
        uint2 o;
        o.x = pk2(f.x, f.y);
        o.y = pk2(f.z, f.w);
        d[i] = o;
    }
}

// ---------- build x = [u_t | emb[s_i]] as bf16 [65536][1536] ----------
__global__ __launch_bounds__(256) void xbuild(const float* __restrict__ u_t,
                                              const float* __restrict__ emb,
                                              const int* __restrict__ s_i,
                                              u16* __restrict__ xb) {
    const long u = (long)blockIdx.x * blockDim.x + threadIdx.x;
    const int row = (int)(u / 192);
    const int c8 = (int)(u % 192);
    const float* src = (c8 < 96) ? (u_t + (long)row * 768 + c8 * 8)
                                 : (emb + (long)s_i[row] * 768 + (c8 - 96) * 8);
    float4 f0 = ((const float4*)src)[0];
    float4 f1 = ((const float4*)src)[1];
    uint4 o;
    o.x = pk2(f0.x, f0.y);
    o.y = pk2(f0.z, f0.w);
    o.z = pk2(f1.x, f1.y);
    o.w = pk2(f1.z, f1.w);
    *(uint4*)(xb + u * 8) = o;
}

// ---------- 256x256 8-phase GEMM:  out = act(A @ B^T + bias) ----------
// A [M][LDK] bf16, B [TN*256][LDK] bf16. EPI 0: GELU->bf16, EPI 1: bias->f32.
// LDS layout: lds[buf][A/B][ks][256*32 u16], swizzled chunks: c' = c ^ ((row>>1)&3).
template <int LDK, int NT, int TN, int EPI>
__global__ __launch_bounds__(512, 2) void gemm256(
    const u16* __restrict__ Ag, const u16* __restrict__ Bg,
    const float* __restrict__ bias, u16* __restrict__ outb,
    float* __restrict__ outf) {
    __shared__ __align__(16) u16 lds[65536];  // 128 KiB

    const int tid = threadIdx.x;
    const int lane = tid & 63;
    const int wv = tid >> 6;
    const int wm = wv >> 2;  // 0..1
    const int wn = wv & 3;   // 0..3

    const int cpx = (int)gridDim.x >> 3;  // grid % 8 == 0
    const int tile = ((int)blockIdx.x & 7) * cpx + ((int)blockIdx.x >> 3);
    const int tm = tile / TN, tn = tile % TN;
    const long rowBase = (long)tm * 256;
    const long colBase = (long)tn * 256;

    // --- staging map: thread -> (row = tid>>2 [+128], swizzled 16B chunk) ---
    const int srow = tid >> 2;
    const int gch = (tid & 3) ^ ((tid >> 3) & 3);
    const u16* pA = Ag + (rowBase + srow) * (long)LDK + gch * 8;
    const u16* pB = Bg + (colBase + srow) * (long)LDK + gch * 8;
    const int dstBase = wv * 512;  // u16 units within 8KB sub-block

    auto stageA = [&](int kt, int ks, int b) {
        const u16* s = pA + kt * 64 + ks * 32;
        u16* d = lds + b * 32768 + ks * 8192 + dstBase;
        gl_lds16(s, d);
        gl_lds16(s + (long)128 * LDK, d + 4096);
    };
    auto stageB = [&](int kt, int ks, int b) {
        const u16* s = pB + kt * 64 + ks * 32;
        u16* d = lds + b * 32768 + 16384 + ks * 8192 + dstBase;
        gl_lds16(s, d);
        gl_lds16(s + (long)128 * LDK, d + 4096);
    };

    // --- fragment read offsets (u16 units, relative to 8KB ks-region) ---
    const int l15 = lane & 15, lc = lane >> 4;
    int offA[8], offB[4];
#pragma unroll
    for (int i = 0; i < 8; ++i) {
        int r = wm * 128 + i * 16 + l15;
        offA[i] = r * 32 + ((lc ^ ((r >> 1) & 3)) << 3);
    }
#pragma unroll
    for (int n = 0; n < 4; ++n) {
        int r = wn * 64 + n * 16 + l15;
        offB[n] = r * 32 + ((lc ^ ((r >> 1) & 3)) << 3);
    }

    f32x4 acc[8][4];
    const f32x4 zero = {0.f, 0.f, 0.f, 0.f};
#pragma unroll
    for (int m = 0; m < 8; ++m)
#pragma unroll
        for (int n = 0; n < 4; ++n) acc[m][n] = zero;

    // --- prologue: stage tile 0 fully; wait k0 halves (k1 stays in flight) ---
    stageA(0, 0, 0);
    stageB(0, 0, 0);
    stageA(0, 1, 0);
    stageB(0, 1, 0);
    WAITV4();
    BAR();

    bf16x8 bA[4], bB[4];
    for (int kt = 0; kt < NT; ++kt) {
        const int b = kt & 1;
        const u16* rA0 = lds + b * 32768;
        const u16* rB0 = rA0 + 16384;
        const u16* rA1 = rA0 + 8192;
        const u16* rB1 = rB0 + 8192;
        const bool pf = (kt + 1 < NT);

        // ---- P0: ks0, m-half0 (reads B ks0 too) ----
#pragma unroll
        for (int n = 0; n < 4; ++n) bB[n] = *(const bf16x8*)(rB0 + offB[n]);
#pragma unroll
        for (int m = 0; m < 4; ++m) bA[m] = *(const bf16x8*)(rA0 + offA[m]);
        if (pf) stageA(kt + 1, 0, b ^ 1);
        BAR();
        WAITL();
        __builtin_amdgcn_s_setprio(1);
#pragma unroll
        for (int m = 0; m < 4; ++m)
#pragma unroll
            for (int n = 0; n < 4; ++n)
                acc[m][n] = __builtin_amdgcn_mfma_f32_16x16x32_bf16(bA[m], bB[n], acc[m][n], 0, 0, 0);
        __builtin_amdgcn_s_setprio(0);
        BAR();

        // ---- P1: ks0, m-half1 ----
#pragma unroll
        for (int m = 0; m < 4; ++m) bA[m] = *(const bf16x8*)(rA0 + offA[4 + m]);
        if (pf) stageB(kt + 1, 0, b ^ 1);
        BAR();
        WAITL();
        __builtin_amdgcn_s_setprio(1);
#pragma unroll
        for (int m = 0; m < 4; ++m)
#pragma unroll
            for (int n = 0; n < 4; ++n)
                acc[4 + m][n] = __builtin_amdgcn_mfma_f32_16x16x32_bf16(bA[m], bB[n], acc[4 + m][n], 0, 0, 0);
        __builtin_amdgcn_s_setprio(0);
        // tile t ks1 must land. pf: 4 newer loads (t+1 ks0) stay in flight.
        // Last tile: only t ks1 outstanding -> vmcnt(4) would be a NO-OP race;
        // must drain fully. (R3 bug.)
        if (pf) { WAITV4(); } else { WAITV0(); }
        BAR();

        // ---- P2: ks1, m-half0 (reads B ks1 too) ----
#pragma unroll
        for (int n = 0; n < 4; ++n) bB[n] = *(const bf16x8*)(rB1 + offB[n]);
#pragma unroll
        for (int m = 0; m < 4; ++m) bA[m] = *(const bf16x8*)(rA1 + offA[m]);
        if (pf) stageA(kt + 1, 1, b ^ 1);
        BAR();
        WAITL();
        __builtin_amdgcn_s_setprio(1);
#pragma unroll
        for (int m = 0; m < 4; ++m)
#pragma unroll
            for (int n = 0; n < 4; ++n)
                acc[m][n] = __builtin_amdgcn_mfma_f32_16x16x32_bf16(bA[m], bB[n], acc[m][n], 0, 0, 0);
        __builtin_amdgcn_s_setprio(0);
        BAR();

        // ---- P3: ks1, m-half1 ----
#pragma unroll
        for (int m = 0; m < 4; ++m) bA[m] = *(const bf16x8*)(rA1 + offA[4 + m]);
        if (pf) stageB(kt + 1, 1, b ^ 1);
        BAR();
        WAITL();
        __builtin_amdgcn_s_setprio(1);
#pragma unroll
        for (int m = 0; m < 4; ++m)
#pragma unroll
            for (int n = 0; n < 4; ++n)
                acc[4 + m][n] = __builtin_amdgcn_mfma_f32_16x16x32_bf16(bA[m], bB[n], acc[4 + m][n], 0, 0, 0);
        __builtin_amdgcn_s_setprio(0);
        // t+1 ks0 must land for next P0; t+1 ks1 (4 loads) stays in flight.
        if (pf) { WAITV4(); } else { WAITV0(); }
        BAR();
    }

    // ---- epilogue ----
    const int N = TN * 256;
#pragma unroll
    for (int n = 0; n < 4; ++n) {
        long gc = colBase + wn * 64 + n * 16 + l15;
        float bv = bias[gc];
#pragma unroll
        for (int i = 0; i < 8; ++i) {
            long gr = rowBase + wm * 128 + i * 16 + (lc << 2);
#pragma unroll
            for (int j = 0; j < 4; ++j) {
                float v = acc[i][n][j] + bv;
                if constexpr (EPI == 0) {
                    v = 0.5f * v * (1.0f + erff(v * 0.70710678118f));
                    outb[(gr + j) * N + gc] = f2bf(v);
                } else {
                    outf[(gr + j) * N + gc] = v;
                }
            }
        }
    }
}

// ---------- LayerNorm (in place) + scatter-add into updated ----------
__global__ __launch_bounds__(256) void ln_scatter(float* __restrict__ y,
                                                  const float* __restrict__ gamma,
                                                  const float* __restrict__ beta,
                                                  const int* __restrict__ s_i,
                                                  float* __restrict__ upd) {
    const int lane = threadIdx.x & 63;
    const long row = (long)blockIdx.x * 4 + (threadIdx.x >> 6);
    const long base = row * 768;
    float v[12];
#pragma unroll
    for (int i = 0; i < 12; ++i) v[i] = y[base + i * 64 + lane];
    float s = 0.f, q = 0.f;
#pragma unroll
    for (int i = 0; i < 12; ++i) { s += v[i]; q += v[i] * v[i]; }
#pragma unroll
    for (int off = 32; off > 0; off >>= 1) {
        s += __shfl_xor(s, off, 64);
        q += __shfl_xor(q, off, 64);
    }
    const float mu = s * (1.f / 768.f);
    const float var = q * (1.f / 768.f) - mu * mu;
    const float inv = rsqrtf(var + 1e-5f);
    const long si = s_i[row];
#pragma unroll
    for (int i = 0; i < 12; ++i) {
        int c = i * 64 + lane;
        float r = (v[i] - mu) * inv * gamma[c] + beta[c];
        y[base + c] = r;
        atomicAdd(&upd[si * 768 + c], r);
    }
}

// ---------- copy speaker_embeddings -> updated ----------
__global__ void copy4(const float4* __restrict__ s, float4* __restrict__ d, long n) {
    long i = (long)blockIdx.x * blockDim.x + threadIdx.x;
    long stride = (long)gridDim.x * blockDim.x;
    for (; i < n; i += stride) d[i] = s[i];
}

extern "C" void kernel_launch(void* const* d_in, const int* in_sizes, int n_in,
                              void* d_out, int out_size, void* d_ws, size_t ws_size,
                              hipStream_t stream) {
    const float* u_t = (const float*)d_in[0];
    const int* s_i = (const int*)d_in[1];
    const float* emb = (const float*)d_in[2];
    const float* W1 = (const float*)d_in[3];
    const float* b1 = (const float*)d_in[4];
    const float* W2 = (const float*)d_in[5];
    const float* b2 = (const float*)d_in[6];
    const float* gamma = (const float*)d_in[7];
    const float* beta = (const float*)d_in[8];

    float* out = (float*)d_out;
    float* newh = out;             // [65536,768] f32 (y, then LN in place)
    float* upd = out + 50331648L;  // [262144,768] f32 (scratch first, final last)

    u16* base = (u16*)upd;
    u16* hbuf = base;                  // [65536,2048] bf16
    u16* xb = base + 134217728L;       // [65536,1536] bf16
    u16* w1b = base + 234881024L;      // [2048,1536] bf16
    u16* w2b = base + 238026752L;      // [768,2048] bf16

    cvtbf<<<1024, 256, 0, stream>>>((const float4*)W1, (uint2*)w1b, 786432);
    cvtbf<<<1024, 256, 0, stream>>>((const float4*)W2, (uint2*)w2b, 393216);
    xbuild<<<49152, 256, 0, stream>>>(u_t, emb, s_i, xb);
    // GEMM1: M=65536, N=2048, K=1536 -> 256x8 = 2048 tiles
    gemm256<1536, 24, 8, 0><<<2048, 512, 0, stream>>>(xb, w1b, b1, hbuf, nullptr);
    // GEMM2: M=65536, N=768, K=2048 -> 256x3 = 768 tiles
    gemm256<2048, 32, 3, 1><<<768, 512, 0, stream>>>(hbuf, w2b, b2, nullptr, newh);
    copy4<<<2048, 256, 0, stream>>>((const float4*)emb, (float4*)upd, 50331648L);
    ln_scatter<<<16384, 256, 0, stream>>>(newh, gamma, beta, s_i, upd);
}